// Round 9
// baseline (660.404 us; speedup 1.0000x reference)
//
#include <hip/hip_runtime.h>
#include <hip/hip_bf16.h>
#include <stdint.h>
#include <stddef.h>

typedef short short8 __attribute__((ext_vector_type(8)));
typedef float f32x4 __attribute__((ext_vector_type(4)));

#define SROWS 65536
#define TROWS 8192
#define HDIM  1024
#define KDIM  2048   // concatenated K: [edu | h]
#define NDIM  4096   // c = 4*j + gate
#define NT    (KDIM / 64)

__device__ __forceinline__ unsigned short f2bf(float f) {
  union { float f; uint32_t u; } v; v.f = f;
  uint32_t u = v.u;
  uint32_t r = (u + 0x7FFFu + ((u >> 16) & 1u)) >> 16;
  return (unsigned short)r;
}

__device__ __forceinline__ float fast_sigmoid(float x) {
  return __builtin_amdgcn_rcpf(1.0f + __builtin_amdgcn_exp2f(-1.44269504f * x));
}
__device__ __forceinline__ float fast_tanh(float x) {
  return 1.0f - 2.0f * __builtin_amdgcn_rcpf(1.0f + __builtin_amdgcn_exp2f(2.88539008f * x));
}

// ---------------- small prep kernels ----------------

__global__ __launch_bounds__(256) void k_initlp(int* lp) {
  int i = blockIdx.x * 256 + threadIdx.x;
  if (i < SROWS) lp[i] = -1;
}

__global__ __launch_bounds__(256) void k_lp(const int* __restrict__ sid, int* lp) {
  int i = blockIdx.x * 256 + threadIdx.x;
  if (i < TROWS) atomicMax(&lp[sid[i]], i);
}

// per-row "untouched" bitmask: bit r of flagb[r>>6] = (lp[r] < 0)
__global__ __launch_bounds__(256) void k_flags(const int* __restrict__ lp,
                                               unsigned long long* __restrict__ flagb) {
  int i = blockIdx.x * 256 + threadIdx.x;
  unsigned long long m = __ballot(lp[i] < 0);
  if ((threadIdx.x & 63) == 0) flagb[i >> 6] = m;
}

__global__ __launch_bounds__(256) void k_bias(const float* __restrict__ bih,
                                              const float* __restrict__ bhh,
                                              float* __restrict__ btab) {
  int j = blockIdx.x * 256 + threadIdx.x;
  if (j < HDIM) {
    btab[4*j+0] = bih[j] + bhh[j];
    btab[4*j+1] = bih[j+HDIM] + bhh[j+HDIM];
    btab[4*j+2] = bih[j+2*HDIM];
    btab[4*j+3] = bhh[j+2*HDIM];
  }
}

__global__ __launch_bounds__(256) void k_build_A(const float* __restrict__ edu,
                                                 const float* __restrict__ mem,
                                                 const int* __restrict__ sid,
                                                 unsigned short* __restrict__ Ac) {
  const int idx = blockIdx.x * 256 + threadIdx.x;
  const int t  = idx >> 8;
  const int k0 = (idx & 255) << 3;
  const float* src;
  if (k0 < HDIM) src = edu + (size_t)t * HDIM + k0;
  else           src = mem + (size_t)sid[t] * HDIM + (k0 - HDIM);
  f32x4 f0 = *(const f32x4*)src;
  f32x4 f1 = *(const f32x4*)(src + 4);
  short8 v;
  v[0]=(short)f2bf(f0[0]); v[1]=(short)f2bf(f0[1]); v[2]=(short)f2bf(f0[2]); v[3]=(short)f2bf(f0[3]);
  v[4]=(short)f2bf(f1[0]); v[5]=(short)f2bf(f1[1]); v[6]=(short)f2bf(f1[2]); v[7]=(short)f2bf(f1[3]);
  *(short8*)(Ac + (size_t)idx * 8) = v;
}

__global__ __launch_bounds__(256) void k_build_B(const float* __restrict__ Wih,
                                                 const float* __restrict__ Whh,
                                                 unsigned short* __restrict__ Bc) {
  const int idx = blockIdx.x * 256 + threadIdx.x;
  const int c  = idx >> 8;
  const int k0 = (idx & 255) << 3;
  const int j  = c >> 2;
  const int g  = c & 3;
  const float* src = nullptr;
  if (g == 0)      src = (k0 < HDIM) ? Wih + (size_t)j * HDIM + k0
                                     : Whh + (size_t)j * HDIM + (k0 - HDIM);
  else if (g == 1) src = (k0 < HDIM) ? Wih + (size_t)(j + HDIM) * HDIM + k0
                                     : Whh + (size_t)(j + HDIM) * HDIM + (k0 - HDIM);
  else if (g == 2) { if (k0 < HDIM)  src = Wih + (size_t)(j + 2*HDIM) * HDIM + k0; }
  else             { if (k0 >= HDIM) src = Whh + (size_t)(j + 2*HDIM) * HDIM + (k0 - HDIM); }
  short8 v = (short8)0;
  if (src) {
    f32x4 f0 = *(const f32x4*)src;
    f32x4 f1 = *(const f32x4*)(src + 4);
    v[0]=(short)f2bf(f0[0]); v[1]=(short)f2bf(f0[1]); v[2]=(short)f2bf(f0[2]); v[3]=(short)f2bf(f0[3]);
    v[4]=(short)f2bf(f1[0]); v[5]=(short)f2bf(f1[1]); v[6]=(short)f2bf(f1[2]); v[7]=(short)f2bf(f1[3]);
  }
  *(short8*)(Bc + (size_t)idx * 8) = v;
}

// ---------------- wave-specialized GEMM + copy (spill-fixed) ----------------
// 768 threads, __launch_bounds__(768) -> 12 waves = 3/SIMD -> VGPR cap ~170 (no spill).
// Waves 0..7: r8's verified 256x256 8-phase GEMM (BK=64, counted vmcnt(4),
//   (row&7)<<4 swizzle both sides, setprio). Waves 8..11: barrier-matched nt
//   streaming copy of this block's 128 untouched rows.
// Barrier ledger: GEMM = 1 + 32*8 + 1 + 16 = 274 ; copy = 127*2 + 2 + 18 = 274.

#define FENCE() asm volatile("" ::: "memory")
#define BAR()   __builtin_amdgcn_s_barrier()
#define LGKM0() asm volatile("s_waitcnt lgkmcnt(0)" ::: "memory")
#define VM(N)   asm volatile("s_waitcnt vmcnt(" #N ")" ::: "memory")

#define STAGE(p0, p1, ldsoff)                                                              \
  __builtin_amdgcn_global_load_lds((const __attribute__((address_space(1))) void*)(p0),   \
      (__attribute__((address_space(3))) void*)(smem + (ldsoff) + w * 1024), 16, 0, 0);    \
  __builtin_amdgcn_global_load_lds((const __attribute__((address_space(1))) void*)(p1),   \
      (__attribute__((address_space(3))) void*)(smem + (ldsoff) + 8192 + w * 1024), 16, 0, 0);

#define LDF(base, frag, koff) (*(const short8*)(smem + (base) + (size_t)(frag) * 2048 + (koff)))

__global__ __launch_bounds__(768)
void k_fused(const unsigned short* __restrict__ Ac,
             const unsigned short* __restrict__ Bc,
             const float* __restrict__ mem,
             const int* __restrict__ sid,
             const int* __restrict__ lp,
             const unsigned long long* __restrict__ flagb,
             const float* __restrict__ btab,
             float* __restrict__ out) {
  extern __shared__ char smem[];
  const int tid = threadIdx.x;
  const int bid = blockIdx.x;
  const int w   = tid >> 6;

  if (w >= 8) {
    // ===== copy waves (8..11): 128 rows/block, barrier-matched, nt stream =====
    const int ct    = tid - 512;            // 0..255
    const int col   = ct << 2;              // f32 column
    const int rbase = bid << 7;             // 128 rows per block
    const unsigned long long f0 = flagb[bid * 2];
    const unsigned long long f1 = flagb[bid * 2 + 1];

    bool pv = (f0 & 1ull) != 0;
    f32x4 d = {0.f, 0.f, 0.f, 0.f};
    if (pv) d = __builtin_nontemporal_load((const f32x4*)&mem[(size_t)rbase * HDIM + col]);
    for (int r = 1; r < 128; ++r) {
      const unsigned long long fw = (r < 64) ? f0 : f1;
      const bool v = (fw >> (r & 63)) & 1ull;
      f32x4 nd = {0.f, 0.f, 0.f, 0.f};
      if (v)  nd = __builtin_nontemporal_load((const f32x4*)&mem[(size_t)(rbase + r) * HDIM + col]);
      if (pv) __builtin_nontemporal_store(d, (f32x4*)&out[(size_t)(rbase + r - 1) * HDIM + col]);
      pv = v; d = nd;
      BAR(); BAR();                         // 127*2 = 254
    }
    if (pv) __builtin_nontemporal_store(d, (f32x4*)&out[(size_t)(rbase + 127) * HDIM + col]);
    BAR(); BAR();                           // 256
    for (int i = 0; i < 18; ++i) BAR();     // 274
    return;
  }

  // ===== GEMM waves (0..7) =====
  const int lane = tid & 63;
  const int wm   = w >> 2;        // M half (0..1)
  const int wn   = w & 3;         // N quarter (0..3)
  const int l15  = lane & 15;
  const int l4   = lane >> 4;

  // XCD-aware swizzle (512 % 8 == 0 -> bijective)
  const int swz = (bid & 7) * 64 + (bid >> 3);
  const int t0  = (swz >> 4) * 256;
  const int c0  = (swz & 15) * 256;

  // ---- staging source mapping (inverse (row&7)<<4 swizzle folded in) ----
  const int srow0 = tid >> 3;
  const int srow1 = 64 + srow0;
  const int scol  = ((tid & 7) * 8) ^ (((tid >> 3) & 7) << 3);

  const unsigned short* pA0r0 = Ac + (size_t)(t0 +       srow0) * KDIM + scol;
  const unsigned short* pA0r1 = Ac + (size_t)(t0 +       srow1) * KDIM + scol;
  const unsigned short* pA1r0 = Ac + (size_t)(t0 + 128 + srow0) * KDIM + scol;
  const unsigned short* pA1r1 = Ac + (size_t)(t0 + 128 + srow1) * KDIM + scol;
  const unsigned short* pB0r0 = Bc + (size_t)(c0 +       srow0) * KDIM + scol;
  const unsigned short* pB0r1 = Bc + (size_t)(c0 +       srow1) * KDIM + scol;
  const unsigned short* pB1r0 = Bc + (size_t)(c0 + 128 + srow0) * KDIM + scol;
  const unsigned short* pB1r1 = Bc + (size_t)(c0 + 128 + srow1) * KDIM + scol;

  // ---- fragment read offsets: col_byte ^= (row&7)<<4 ----
  const int rsw = (l15 & 7) << 4;
  const size_t foff0 = (size_t)l15 * 128 + ((l4 * 16)      ^ rsw);
  const size_t foff1 = (size_t)l15 * 128 + ((64 + l4 * 16) ^ rsw);

  f32x4 acc[8][4];
#pragma unroll
  for (int i = 0; i < 8; i++)
#pragma unroll
    for (int j = 0; j < 4; j++) acc[i][j] = (f32x4){0.f, 0.f, 0.f, 0.f};

  // ---- prologue: tile0 (A0,A1,B0,B1) + tile1 (B0,B1)
  STAGE(pA0r0, pA0r1, 0);
  STAGE(pA1r0, pA1r1, 16384);
  STAGE(pB0r0, pB0r1, 32768);
  STAGE(pB1r0, pB1r1, 49152);
  STAGE(pB0r0 + 64, pB0r1 + 64, 65536 + 32768);
  STAGE(pB1r0 + 64, pB1r1 + 64, 65536 + 49152);
  VM(4);
  FENCE(); BAR();                                   // 1

  for (int t = 0; t < NT; ++t) {
    const int cur = t & 1, nxt = cur ^ 1;
    const size_t abase = (size_t)cur * 65536 + (size_t)wm * 16384;
    const size_t bbase = (size_t)cur * 65536 + 32768 + (size_t)(wn >> 1) * 16384
                       + (size_t)(wn & 1) * 8192;
    const int kt1 = (t + 1 < NT) ? t + 1 : NT - 1;
    const int kt2 = (t + 2 < NT) ? t + 2 : NT - 1;

    short8 bf[4][2];
#pragma unroll
    for (int q = 0; q < 4; q++) {
      const int m0 = 2 * q;
      if (q == 0) {
#pragma unroll
        for (int n = 0; n < 4; n++) {
          bf[n][0] = LDF(bbase, n, foff0);
          bf[n][1] = LDF(bbase, n, foff1);
        }
      }
      short8 af[2][2];
      af[0][0] = LDF(abase, m0,     foff0);
      af[0][1] = LDF(abase, m0,     foff1);
      af[1][0] = LDF(abase, m0 + 1, foff0);
      af[1][1] = LDF(abase, m0 + 1, foff1);

      if (q == 0)      { STAGE(pA0r0 + kt1 * 64, pA0r1 + kt1 * 64, (size_t)nxt * 65536); }
      else if (q == 1) { STAGE(pA1r0 + kt1 * 64, pA1r1 + kt1 * 64, (size_t)nxt * 65536 + 16384); }
      else if (q == 2) { STAGE(pB0r0 + kt2 * 64, pB0r1 + kt2 * 64, (size_t)cur * 65536 + 32768); }
      else             { STAGE(pB1r0 + kt2 * 64, pB1r1 + kt2 * 64, (size_t)cur * 65536 + 49152); }

      FENCE(); BAR();                               // 8 per tile
      LGKM0();
      __builtin_amdgcn_s_setprio(1);
#pragma unroll
      for (int i = 0; i < 2; i++)
#pragma unroll
        for (int n = 0; n < 4; n++) {
          acc[m0 + i][n] = __builtin_amdgcn_mfma_f32_16x16x32_bf16(af[i][0], bf[n][0], acc[m0 + i][n], 0, 0, 0);
          acc[m0 + i][n] = __builtin_amdgcn_mfma_f32_16x16x32_bf16(af[i][1], bf[n][1], acc[m0 + i][n], 0, 0, 0);
        }
      __builtin_amdgcn_s_setprio(0);
      if (q == 3) { VM(4); }
      FENCE(); BAR();
    }
  }

  // ---- drain + epilogue
  VM(0);
  __syncthreads();                                  // 1
  float* epi = (float*)smem;   // [8 waves][16][68]
  const int jfirst = ((c0 + wn * 64) >> 2) + l4 * 4;

#pragma unroll
  for (int mf = 0; mf < 8; mf++) {
#pragma unroll
    for (int nf = 0; nf < 4; nf++)
#pragma unroll
      for (int r = 0; r < 4; r++)
        epi[w * 1088 + (l4 * 4 + r) * 68 + nf * 16 + l15] = acc[mf][nf][r];
    __syncthreads();                                // 8x

    const int trow = t0 + wm * 128 + mf * 16 + l15;
    const int s    = sid[trow];
    const bool wr  = (lp[s] == trow);

    f32x4 q[4];
#pragma unroll
    for (int jj = 0; jj < 4; jj++)
      q[jj] = *(const f32x4*)&epi[w * 1088 + l15 * 68 + l4 * 16 + jj * 4];

    f32x4 hv = *(const f32x4*)&mem[(size_t)s * HDIM + jfirst];
    f32x4 o;
#pragma unroll
    for (int jj = 0; jj < 4; jj++) {
      const int j = jfirst + jj;
      f32x4 bt = *(const f32x4*)&btab[4 * j];
      float rr = fast_sigmoid(q[jj][0] + bt[0]);
      float zz = fast_sigmoid(q[jj][1] + bt[1]);
      float nn = fast_tanh(q[jj][2] + bt[2] + rr * (q[jj][3] + bt[3]));
      o[jj] = (1.0f - zz) * nn + zz * hv[jj];
    }
    if (wr) __builtin_nontemporal_store(o, (f32x4*)&out[(size_t)s * HDIM + jfirst]);
    __syncthreads();                                // 8x
  }
}

// ---------------- launch ----------------

extern "C" void kernel_launch(void* const* d_in, const int* in_sizes, int n_in,
                              void* d_out, int out_size, void* d_ws, size_t ws_size,
                              hipStream_t stream) {
  const float* mem = (const float*)d_in[0];
  const int*   sid = (const int*)d_in[1];
  const float* edu = (const float*)d_in[2];
  const float* Wih = (const float*)d_in[3];
  const float* Whh = (const float*)d_in[4];
  const float* bih = (const float*)d_in[5];
  const float* bhh = (const float*)d_in[6];
  float* out = (float*)d_out;

  char* p = (char*)d_ws;
  unsigned short* Ac = (unsigned short*)p; p += (size_t)TROWS * KDIM * 2;   // 32 MiB
  unsigned short* Bc = (unsigned short*)p; p += (size_t)NDIM * KDIM * 2;    // 16 MiB
  int*   lp   = (int*)p;   p += (size_t)SROWS * 4;                          // 256 KiB
  float* btab = (float*)p; p += (size_t)HDIM * 4 * 4;                       // 16 KiB
  unsigned long long* flagb = (unsigned long long*)p; p += (size_t)(SROWS / 64) * 8; // 8 KiB

  hipFuncSetAttribute((const void*)k_fused, hipFuncAttributeMaxDynamicSharedMemorySize, 131072);

  hipLaunchKernelGGL(k_initlp, dim3(SROWS / 256), dim3(256), 0, stream, lp);
  hipLaunchKernelGGL(k_lp, dim3(TROWS / 256), dim3(256), 0, stream, sid, lp);
  hipLaunchKernelGGL(k_flags, dim3(SROWS / 256), dim3(256), 0, stream, lp, flagb);
  hipLaunchKernelGGL(k_bias, dim3(4), dim3(256), 0, stream, bih, bhh, btab);
  hipLaunchKernelGGL(k_build_A, dim3((TROWS * KDIM / 8) / 256), dim3(256), 0, stream, edu, mem, sid, Ac);
  hipLaunchKernelGGL(k_build_B, dim3((NDIM * KDIM / 8) / 256), dim3(256), 0, stream, Wih, Whh, Bc);
  hipLaunchKernelGGL(k_fused, dim3(512), dim3(768), 131072, stream,
                     Ac, Bc, mem, sid, lp, flagb, btab, out);
}

// Round 10
// 230.678 us; speedup vs baseline: 2.8629x; 2.8629x over previous
//
#include <hip/hip_runtime.h>
#include <hip/hip_bf16.h>
#include <stdint.h>
#include <stddef.h>

typedef short short8 __attribute__((ext_vector_type(8)));
typedef float f32x4 __attribute__((ext_vector_type(4)));

#define SROWS 65536
#define TROWS 8192
#define HDIM  1024
#define KDIM  2048   // concatenated K: [edu | h]
#define NDIM  4096   // c = 4*j + gate
#define NT    (KDIM / 64)

__device__ __forceinline__ unsigned short f2bf(float f) {
  union { float f; uint32_t u; } v; v.f = f;
  uint32_t u = v.u;
  uint32_t r = (u + 0x7FFFu + ((u >> 16) & 1u)) >> 16;
  return (unsigned short)r;
}

__device__ __forceinline__ float fast_sigmoid(float x) {
  return __builtin_amdgcn_rcpf(1.0f + __builtin_amdgcn_exp2f(-1.44269504f * x));
}
__device__ __forceinline__ float fast_tanh(float x) {
  return 1.0f - 2.0f * __builtin_amdgcn_rcpf(1.0f + __builtin_amdgcn_exp2f(2.88539008f * x));
}

// ---------------- small prep kernels ----------------

__global__ __launch_bounds__(256) void k_initlp(int* lp) {
  int i = blockIdx.x * 256 + threadIdx.x;
  if (i < SROWS) lp[i] = -1;
}

__global__ __launch_bounds__(256) void k_lp(const int* __restrict__ sid, int* lp) {
  int i = blockIdx.x * 256 + threadIdx.x;
  if (i < TROWS) atomicMax(&lp[sid[i]], i);
}

// per-row "untouched" bitmask: bit r of flagb[r>>6] = (lp[r] < 0)
__global__ __launch_bounds__(256) void k_flags(const int* __restrict__ lp,
                                               unsigned long long* __restrict__ flagb) {
  int i = blockIdx.x * 256 + threadIdx.x;
  unsigned long long m = __ballot(lp[i] < 0);
  if ((threadIdx.x & 63) == 0) flagb[i >> 6] = m;
}

__global__ __launch_bounds__(256) void k_bias(const float* __restrict__ bih,
                                              const float* __restrict__ bhh,
                                              float* __restrict__ btab) {
  int j = blockIdx.x * 256 + threadIdx.x;
  if (j < HDIM) {
    btab[4*j+0] = bih[j] + bhh[j];
    btab[4*j+1] = bih[j+HDIM] + bhh[j+HDIM];
    btab[4*j+2] = bih[j+2*HDIM];
    btab[4*j+3] = bhh[j+2*HDIM];
  }
}

__global__ __launch_bounds__(256) void k_build_A(const float* __restrict__ edu,
                                                 const float* __restrict__ mem,
                                                 const int* __restrict__ sid,
                                                 unsigned short* __restrict__ Ac) {
  const int idx = blockIdx.x * 256 + threadIdx.x;
  const int t  = idx >> 8;
  const int k0 = (idx & 255) << 3;
  const float* src;
  if (k0 < HDIM) src = edu + (size_t)t * HDIM + k0;
  else           src = mem + (size_t)sid[t] * HDIM + (k0 - HDIM);
  f32x4 f0 = *(const f32x4*)src;
  f32x4 f1 = *(const f32x4*)(src + 4);
  short8 v;
  v[0]=(short)f2bf(f0[0]); v[1]=(short)f2bf(f0[1]); v[2]=(short)f2bf(f0[2]); v[3]=(short)f2bf(f0[3]);
  v[4]=(short)f2bf(f1[0]); v[5]=(short)f2bf(f1[1]); v[6]=(short)f2bf(f1[2]); v[7]=(short)f2bf(f1[3]);
  *(short8*)(Ac + (size_t)idx * 8) = v;
}

__global__ __launch_bounds__(256) void k_build_B(const float* __restrict__ Wih,
                                                 const float* __restrict__ Whh,
                                                 unsigned short* __restrict__ Bc) {
  const int idx = blockIdx.x * 256 + threadIdx.x;
  const int c  = idx >> 8;
  const int k0 = (idx & 255) << 3;
  const int j  = c >> 2;
  const int g  = c & 3;
  const float* src = nullptr;
  if (g == 0)      src = (k0 < HDIM) ? Wih + (size_t)j * HDIM + k0
                                     : Whh + (size_t)j * HDIM + (k0 - HDIM);
  else if (g == 1) src = (k0 < HDIM) ? Wih + (size_t)(j + HDIM) * HDIM + k0
                                     : Whh + (size_t)(j + HDIM) * HDIM + (k0 - HDIM);
  else if (g == 2) { if (k0 < HDIM)  src = Wih + (size_t)(j + 2*HDIM) * HDIM + k0; }
  else             { if (k0 >= HDIM) src = Whh + (size_t)(j + 2*HDIM) * HDIM + (k0 - HDIM); }
  short8 v = (short8)0;
  if (src) {
    f32x4 f0 = *(const f32x4*)src;
    f32x4 f1 = *(const f32x4*)(src + 4);
    v[0]=(short)f2bf(f0[0]); v[1]=(short)f2bf(f0[1]); v[2]=(short)f2bf(f0[2]); v[3]=(short)f2bf(f0[3]);
    v[4]=(short)f2bf(f1[0]); v[5]=(short)f2bf(f1[1]); v[6]=(short)f2bf(f1[2]); v[7]=(short)f2bf(f1[3]);
  }
  *(short8*)(Bc + (size_t)idx * 8) = v;
}

// ---------------- 256x256 8-phase GEMM + gates + scatter + in-loop copy ----------------
// r8's verified GEMM (135us clean) + untouched-row copy in the K-loop with:
//   - DOUBLE-BUFFERED copy registers (set X even tiles, set Y odd) -> no WAR hazard,
//     no compiler-inserted vmcnt(0) drain (the r4/r5 regression mechanism)
//   - predicates from SGPR bitmask (wave-uniform branch, no VMEM dependence)
//   - nt loads/stores (bypass L2)
// VM(4) semantics unchanged: FIFO at tile t q3 = [copy(t-1)x4][A(t+1)x4][B(t+2)x4];
// VM(4) retires copies+A (copies get a full ~3.5us tile of slack).

#define FENCE() asm volatile("" ::: "memory")
#define BAR()   __builtin_amdgcn_s_barrier()
#define LGKM0() asm volatile("s_waitcnt lgkmcnt(0)" ::: "memory")
#define VM(N)   asm volatile("s_waitcnt vmcnt(" #N ")" ::: "memory")

#define STAGE(p0, p1, ldsoff)                                                              \
  __builtin_amdgcn_global_load_lds((const __attribute__((address_space(1))) void*)(p0),   \
      (__attribute__((address_space(3))) void*)(smem + (ldsoff) + w * 1024), 16, 0, 0);    \
  __builtin_amdgcn_global_load_lds((const __attribute__((address_space(1))) void*)(p1),   \
      (__attribute__((address_space(3))) void*)(smem + (ldsoff) + 8192 + w * 1024), 16, 0, 0);

#define LDF(base, frag, koff) (*(const short8*)(smem + (base) + (size_t)(frag) * 2048 + (koff)))

__global__ __launch_bounds__(512, 2)
void k_gru8(const unsigned short* __restrict__ Ac,
            const unsigned short* __restrict__ Bc,
            const float* __restrict__ mem,
            const int* __restrict__ sid,
            const int* __restrict__ lp,
            const unsigned long long* __restrict__ flagb,
            const float* __restrict__ btab,
            float* __restrict__ out) {
  extern __shared__ char smem[];

  const int tid  = threadIdx.x;
  const int lane = tid & 63;
  const int w    = tid >> 6;
  const int wm   = w >> 2;        // M half (0..1)
  const int wn   = w & 3;         // N quarter (0..3)
  const int l15  = lane & 15;
  const int l4   = lane >> 4;

  // XCD-aware swizzle (512 % 8 == 0 -> bijective)
  const int bid = blockIdx.x;
  const int swz = (bid & 7) * 64 + (bid >> 3);
  const int t0  = (swz >> 4) * 256;
  const int c0  = (swz & 15) * 256;

  // ---- staging source mapping (inverse (row&7)<<4 swizzle folded in) ----
  const int srow0 = tid >> 3;
  const int srow1 = 64 + srow0;
  const int scol  = ((tid & 7) * 8) ^ (((tid >> 3) & 7) << 3);

  const unsigned short* pA0r0 = Ac + (size_t)(t0 +       srow0) * KDIM + scol;
  const unsigned short* pA0r1 = Ac + (size_t)(t0 +       srow1) * KDIM + scol;
  const unsigned short* pA1r0 = Ac + (size_t)(t0 + 128 + srow0) * KDIM + scol;
  const unsigned short* pA1r1 = Ac + (size_t)(t0 + 128 + srow1) * KDIM + scol;
  const unsigned short* pB0r0 = Bc + (size_t)(c0 +       srow0) * KDIM + scol;
  const unsigned short* pB0r1 = Bc + (size_t)(c0 +       srow1) * KDIM + scol;
  const unsigned short* pB1r0 = Bc + (size_t)(c0 + 128 + srow0) * KDIM + scol;
  const unsigned short* pB1r1 = Bc + (size_t)(c0 + 128 + srow1) * KDIM + scol;

  // ---- fragment read offsets: col_byte ^= (row&7)<<4 ----
  const int rsw = (l15 & 7) << 4;
  const size_t foff0 = (size_t)l15 * 128 + ((l4 * 16)      ^ rsw);
  const size_t foff1 = (size_t)l15 * 128 + ((64 + l4 * 16) ^ rsw);

  f32x4 acc[8][4];
#pragma unroll
  for (int i = 0; i < 8; i++)
#pragma unroll
    for (int j = 0; j < 4; j++) acc[i][j] = (f32x4){0.f, 0.f, 0.f, 0.f};

  // ---- copy pipeline: 4 rows/tile, 2 register sets (X even tiles, Y odd) ----
  const int cbase = bid << 7;                        // 128 rows per block
  const unsigned long long fw0 = flagb[bid * 2];     // rows [cbase, cbase+64)
  const unsigned long long fw1 = flagb[bid * 2 + 1]; // rows [cbase+64, cbase+128)
  const int ccp  = tid >> 8;                         // 0 or 1 (wave-uniform)
  const int ccol = (tid & 255) << 2;                 // f32 column
  f32x4 cpX0, cpX1, cpY0, cpY1;
  bool  vX0 = false, vX1 = false, vY0 = false, vY1 = false;
  int   sX0 = 0, sX1 = 0, sY0 = 0, sY1 = 0;

  // ---- prologue: tile0 (A0,A1,B0,B1) + tile1 (B0,B1)
  STAGE(pA0r0, pA0r1, 0);
  STAGE(pA1r0, pA1r1, 16384);
  STAGE(pB0r0, pB0r1, 32768);
  STAGE(pB1r0, pB1r1, 49152);
  STAGE(pB0r0 + 64, pB0r1 + 64, 65536 + 32768);
  STAGE(pB1r0 + 64, pB1r1 + 64, 65536 + 49152);
  VM(4);
  FENCE(); BAR();

  for (int t = 0; t < NT; ++t) {
    const int cur = t & 1, nxt = cur ^ 1;
    const size_t abase = (size_t)cur * 65536 + (size_t)wm * 16384;
    const size_t bbase = (size_t)cur * 65536 + 32768 + (size_t)(wn >> 1) * 16384
                       + (size_t)(wn & 1) * 8192;
    const int kt1 = (t + 1 < NT) ? t + 1 : NT - 1;
    const int kt2 = (t + 2 < NT) ? t + 2 : NT - 1;

    short8 bf[4][2];
#pragma unroll
    for (int q = 0; q < 4; q++) {
      const int m0 = 2 * q;
      if (q == 0) {
#pragma unroll
        for (int n = 0; n < 4; n++) {
          bf[n][0] = LDF(bbase, n, foff0);
          bf[n][1] = LDF(bbase, n, foff1);
        }
      }
      short8 af[2][2];
      af[0][0] = LDF(abase, m0,     foff0);
      af[0][1] = LDF(abase, m0,     foff1);
      af[1][0] = LDF(abase, m0 + 1, foff0);
      af[1][1] = LDF(abase, m0 + 1, foff1);

      if (q == 0)      { STAGE(pA0r0 + kt1 * 64, pA0r1 + kt1 * 64, (size_t)nxt * 65536); }
      else if (q == 1) { STAGE(pA1r0 + kt1 * 64, pA1r1 + kt1 * 64, (size_t)nxt * 65536 + 16384); }
      else if (q == 2) { STAGE(pB0r0 + kt2 * 64, pB0r1 + kt2 * 64, (size_t)cur * 65536 + 32768); }
      else             { STAGE(pB1r0 + kt2 * 64, pB1r1 + kt2 * 64, (size_t)cur * 65536 + 49152); }

      FENCE(); BAR();
      LGKM0();
      __builtin_amdgcn_s_setprio(1);
#pragma unroll
      for (int i = 0; i < 2; i++)
#pragma unroll
        for (int n = 0; n < 4; n++) {
          acc[m0 + i][n] = __builtin_amdgcn_mfma_f32_16x16x32_bf16(af[i][0], bf[n][0], acc[m0 + i][n], 0, 0, 0);
          acc[m0 + i][n] = __builtin_amdgcn_mfma_f32_16x16x32_bf16(af[i][1], bf[n][1], acc[m0 + i][n], 0, 0, 0);
        }
      __builtin_amdgcn_s_setprio(0);
      if (q == 3) {
        VM(4);   // retires copy(t-1) + A(t+1); leaves B(t+2) in flight
        const int rr0 = 4 * t + ccp, rr1 = rr0 + 2;
        const unsigned long long fwt = (t < 16) ? fw0 : fw1;
        const bool nv0 = (fwt >> (rr0 & 63)) & 1ull;
        const bool nv1 = (fwt >> (rr1 & 63)) & 1ull;
        if ((t & 1) == 0) {
          // store set Y (loaded at t-1, retired by VM(4) at this tile), load set X
          if (vY0) __builtin_nontemporal_store(cpY0, (f32x4*)&out[(size_t)sY0 * HDIM + ccol]);
          if (vY1) __builtin_nontemporal_store(cpY1, (f32x4*)&out[(size_t)sY1 * HDIM + ccol]);
          vX0 = nv0; vX1 = nv1; sX0 = cbase + rr0; sX1 = cbase + rr1;
          if (vX0) cpX0 = __builtin_nontemporal_load((const f32x4*)&mem[(size_t)sX0 * HDIM + ccol]);
          if (vX1) cpX1 = __builtin_nontemporal_load((const f32x4*)&mem[(size_t)sX1 * HDIM + ccol]);
        } else {
          // store set X, load set Y
          if (vX0) __builtin_nontemporal_store(cpX0, (f32x4*)&out[(size_t)sX0 * HDIM + ccol]);
          if (vX1) __builtin_nontemporal_store(cpX1, (f32x4*)&out[(size_t)sX1 * HDIM + ccol]);
          vY0 = nv0; vY1 = nv1; sY0 = cbase + rr0; sY1 = cbase + rr1;
          if (vY0) cpY0 = __builtin_nontemporal_load((const f32x4*)&mem[(size_t)sY0 * HDIM + ccol]);
          if (vY1) cpY1 = __builtin_nontemporal_load((const f32x4*)&mem[(size_t)sY1 * HDIM + ccol]);
        }
      }
      FENCE(); BAR();
    }
  }

  // ---- drain: final copy stores (NT-1=31 odd -> set Y pending), then epilogue
  VM(0);
  if (vY0) __builtin_nontemporal_store(cpY0, (f32x4*)&out[(size_t)sY0 * HDIM + ccol]);
  if (vY1) __builtin_nontemporal_store(cpY1, (f32x4*)&out[(size_t)sY1 * HDIM + ccol]);
  __syncthreads();
  float* epi = (float*)smem;   // [8 waves][16][68]
  const int jfirst = ((c0 + wn * 64) >> 2) + l4 * 4;

#pragma unroll
  for (int mf = 0; mf < 8; mf++) {
#pragma unroll
    for (int nf = 0; nf < 4; nf++)
#pragma unroll
      for (int r = 0; r < 4; r++)
        epi[w * 1088 + (l4 * 4 + r) * 68 + nf * 16 + l15] = acc[mf][nf][r];
    __syncthreads();

    const int trow = t0 + wm * 128 + mf * 16 + l15;
    const int s    = sid[trow];
    const bool wr  = (lp[s] == trow);

    f32x4 q[4];
#pragma unroll
    for (int jj = 0; jj < 4; jj++)
      q[jj] = *(const f32x4*)&epi[w * 1088 + l15 * 68 + l4 * 16 + jj * 4];

    f32x4 hv = *(const f32x4*)&mem[(size_t)s * HDIM + jfirst];
    f32x4 o;
#pragma unroll
    for (int jj = 0; jj < 4; jj++) {
      const int j = jfirst + jj;
      f32x4 bt = *(const f32x4*)&btab[4 * j];
      float rr = fast_sigmoid(q[jj][0] + bt[0]);
      float zz = fast_sigmoid(q[jj][1] + bt[1]);
      float nn = fast_tanh(q[jj][2] + bt[2] + rr * (q[jj][3] + bt[3]));
      o[jj] = (1.0f - zz) * nn + zz * hv[jj];
    }
    if (wr) __builtin_nontemporal_store(o, (f32x4*)&out[(size_t)s * HDIM + jfirst]);
    __syncthreads();
  }
}

// ---------------- launch ----------------

extern "C" void kernel_launch(void* const* d_in, const int* in_sizes, int n_in,
                              void* d_out, int out_size, void* d_ws, size_t ws_size,
                              hipStream_t stream) {
  const float* mem = (const float*)d_in[0];
  const int*   sid = (const int*)d_in[1];
  const float* edu = (const float*)d_in[2];
  const float* Wih = (const float*)d_in[3];
  const float* Whh = (const float*)d_in[4];
  const float* bih = (const float*)d_in[5];
  const float* bhh = (const float*)d_in[6];
  float* out = (float*)d_out;

  char* p = (char*)d_ws;
  unsigned short* Ac = (unsigned short*)p; p += (size_t)TROWS * KDIM * 2;   // 32 MiB
  unsigned short* Bc = (unsigned short*)p; p += (size_t)NDIM * KDIM * 2;    // 16 MiB
  int*   lp   = (int*)p;   p += (size_t)SROWS * 4;                          // 256 KiB
  float* btab = (float*)p; p += (size_t)HDIM * 4 * 4;                       // 16 KiB
  unsigned long long* flagb = (unsigned long long*)p; p += (size_t)(SROWS / 64) * 8; // 8 KiB

  hipFuncSetAttribute((const void*)k_gru8, hipFuncAttributeMaxDynamicSharedMemorySize, 131072);

  hipLaunchKernelGGL(k_initlp, dim3(SROWS / 256), dim3(256), 0, stream, lp);
  hipLaunchKernelGGL(k_lp, dim3(TROWS / 256), dim3(256), 0, stream, sid, lp);
  hipLaunchKernelGGL(k_flags, dim3(SROWS / 256), dim3(256), 0, stream, lp, flagb);
  hipLaunchKernelGGL(k_bias, dim3(4), dim3(256), 0, stream, bih, bhh, btab);
  hipLaunchKernelGGL(k_build_A, dim3((TROWS * KDIM / 8) / 256), dim3(256), 0, stream, edu, mem, sid, Ac);
  hipLaunchKernelGGL(k_build_B, dim3((NDIM * KDIM / 8) / 256), dim3(256), 0, stream, Wih, Whh, Bc);
  hipLaunchKernelGGL(k_gru8, dim3(512), dim3(512), 131072, stream,
                     Ac, Bc, mem, sid, lp, flagb, btab, out);
}

// Round 11
// 207.390 us; speedup vs baseline: 3.1844x; 1.1123x over previous
//
#include <hip/hip_runtime.h>
#include <hip/hip_bf16.h>
#include <stdint.h>
#include <stddef.h>

typedef short short8 __attribute__((ext_vector_type(8)));
typedef float f32x4 __attribute__((ext_vector_type(4)));

#define SROWS 65536
#define TROWS 8192
#define HDIM  1024
#define KDIM  2048   // concatenated K: [edu | h]
#define NT    32     // K-tiles of 64
#define BUF   57344  // per-buffer LDS: A 32K + Brz 16K + Bn 8K

__device__ __forceinline__ unsigned short f2bf(float f) {
  union { float f; uint32_t u; } v; v.f = f;
  uint32_t u = v.u;
  uint32_t r = (u + 0x7FFFu + ((u >> 16) & 1u)) >> 16;
  return (unsigned short)r;
}

__device__ __forceinline__ float fast_sigmoid(float x) {
  return __builtin_amdgcn_rcpf(1.0f + __builtin_amdgcn_exp2f(-1.44269504f * x));
}
__device__ __forceinline__ float fast_tanh(float x) {
  return 1.0f - 2.0f * __builtin_amdgcn_rcpf(1.0f + __builtin_amdgcn_exp2f(2.88539008f * x));
}

// ---------------- small prep kernels ----------------

__global__ __launch_bounds__(256) void k_initlp(int* lp) {
  int i = blockIdx.x * 256 + threadIdx.x;
  if (i < SROWS) lp[i] = -1;
}

__global__ __launch_bounds__(256) void k_lp(const int* __restrict__ sid, int* lp) {
  int i = blockIdx.x * 256 + threadIdx.x;
  if (i < TROWS) atomicMax(&lp[sid[i]], i);
}

__global__ __launch_bounds__(256) void k_flags(const int* __restrict__ lp,
                                               unsigned long long* __restrict__ flagb) {
  int i = blockIdx.x * 256 + threadIdx.x;
  unsigned long long m = __ballot(lp[i] < 0);
  if ((threadIdx.x & 63) == 0) flagb[i >> 6] = m;
}

__global__ __launch_bounds__(256) void k_bias(const float* __restrict__ bih,
                                              const float* __restrict__ bhh,
                                              float* __restrict__ btab) {
  int j = blockIdx.x * 256 + threadIdx.x;
  if (j < HDIM) {
    btab[4*j+0] = bih[j] + bhh[j];
    btab[4*j+1] = bih[j+HDIM] + bhh[j+HDIM];
    btab[4*j+2] = bih[j+2*HDIM];
    btab[4*j+3] = bhh[j+2*HDIM];
  }
}

__global__ __launch_bounds__(256) void k_build_A(const float* __restrict__ edu,
                                                 const float* __restrict__ mem,
                                                 const int* __restrict__ sid,
                                                 unsigned short* __restrict__ Ac) {
  const int idx = blockIdx.x * 256 + threadIdx.x;
  const int t  = idx >> 8;
  const int k0 = (idx & 255) << 3;
  const float* src;
  if (k0 < HDIM) src = edu + (size_t)t * HDIM + k0;
  else           src = mem + (size_t)sid[t] * HDIM + (k0 - HDIM);
  f32x4 f0 = *(const f32x4*)src;
  f32x4 f1 = *(const f32x4*)(src + 4);
  short8 v;
  v[0]=(short)f2bf(f0[0]); v[1]=(short)f2bf(f0[1]); v[2]=(short)f2bf(f0[2]); v[3]=(short)f2bf(f0[3]);
  v[4]=(short)f2bf(f1[0]); v[5]=(short)f2bf(f1[1]); v[6]=(short)f2bf(f1[2]); v[7]=(short)f2bf(f1[3]);
  *(short8*)(Ac + (size_t)idx * 8) = v;
}

// Dense B (no zero padding):
//  Brz[c][k], c=2j+g (g=0:r, 1:z): [Wih_g[j] | Whh_g[j]]   (2048 x 2048)
//  Bn [j][k]:                      [Wih_n[j] | Whh_n[j]]   (1024 x 2048)
__global__ __launch_bounds__(256) void k_build_B2(const float* __restrict__ Wih,
                                                  const float* __restrict__ Whh,
                                                  unsigned short* __restrict__ Brz,
                                                  unsigned short* __restrict__ Bn) {
  const int idx = blockIdx.x * 256 + threadIdx.x;   // 3072 rows x 256 chunks
  const int c  = idx >> 8;
  const int k0 = (idx & 255) << 3;
  const float* src;
  unsigned short* dst;
  if (c < 2048) {
    const int j = c >> 1, g = c & 1;
    const int row = j + g * 1024;
    src = (k0 < HDIM) ? Wih + (size_t)row * HDIM + k0
                      : Whh + (size_t)row * HDIM + (k0 - HDIM);
    dst = Brz + (size_t)c * KDIM + k0;
  } else {
    const int j = c - 2048;
    src = (k0 < HDIM) ? Wih + (size_t)(j + 2*HDIM) * HDIM + k0
                      : Whh + (size_t)(j + 2*HDIM) * HDIM + (k0 - HDIM);
    dst = Bn + (size_t)j * KDIM + k0;
  }
  f32x4 f0 = *(const f32x4*)src;
  f32x4 f1 = *(const f32x4*)(src + 4);
  short8 v;
  v[0]=(short)f2bf(f0[0]); v[1]=(short)f2bf(f0[1]); v[2]=(short)f2bf(f0[2]); v[3]=(short)f2bf(f0[3]);
  v[4]=(short)f2bf(f1[0]); v[5]=(short)f2bf(f1[1]); v[6]=(short)f2bf(f1[2]); v[7]=(short)f2bf(f1[3]);
  *(short8*)dst = v;
}

// ---------------- dense 256x64j 8-phase GEMM + gates + scatter + in-loop copy ----------------
// Per block: 256 t-rows x 64 j's. Per K-tile (64): A 256x64, Brz 128x64, Bn 64x64.
// N-column has TWO accumulators: tiles 0-15 -> i_n (edu half), 16-31 -> h_n (h half),
// selected by static loop split. MFMA/tile = 384 (vs 512 padded, -25%).
// LDS 112 KiB (2 x 56K), (row&7)<<4 swizzle both sides, counted VM(3)/tile,
// r10's double-buffered-register copy pipeline (X even / Y odd tiles, nt ld/st).

#define FENCE() asm volatile("" ::: "memory")
#define BAR()   __builtin_amdgcn_s_barrier()
#define LGKM0() asm volatile("s_waitcnt lgkmcnt(0)" ::: "memory")
#define VM(N)   asm volatile("s_waitcnt vmcnt(" #N ")" ::: "memory")

#define STAGE(p0, p1, ldsoff)                                                              \
  __builtin_amdgcn_global_load_lds((const __attribute__((address_space(1))) void*)(p0),   \
      (__attribute__((address_space(3))) void*)(smem + (ldsoff) + w * 1024), 16, 0, 0);    \
  __builtin_amdgcn_global_load_lds((const __attribute__((address_space(1))) void*)(p1),   \
      (__attribute__((address_space(3))) void*)(smem + (ldsoff) + 8192 + w * 1024), 16, 0, 0);

#define STAGE1(p0, ldsoff)                                                                 \
  __builtin_amdgcn_global_load_lds((const __attribute__((address_space(1))) void*)(p0),   \
      (__attribute__((address_space(3))) void*)(smem + (ldsoff) + w * 1024), 16, 0, 0);

#define LDF(base, frag, koff) (*(const short8*)(smem + (base) + (size_t)(frag) * 2048 + (koff)))

#define MF(a, b, c) __builtin_amdgcn_mfma_f32_16x16x32_bf16(a, b, c, 0, 0, 0)

#define PHASE(m0, STAGE_STMT, TAIL, ACCN)                                     \
  {                                                                           \
    short8 af0a = LDF(abase, (m0),     foff0);                                \
    short8 af0b = LDF(abase, (m0),     foff1);                                \
    short8 af1a = LDF(abase, (m0) + 1, foff0);                                \
    short8 af1b = LDF(abase, (m0) + 1, foff1);                                \
    STAGE_STMT;                                                               \
    FENCE(); BAR();                                                           \
    LGKM0();                                                                  \
    __builtin_amdgcn_s_setprio(1);                                            \
    acc_rz[(m0)][0]   = MF(af0a, bf[0][0], acc_rz[(m0)][0]);                  \
    acc_rz[(m0)][0]   = MF(af0b, bf[0][1], acc_rz[(m0)][0]);                  \
    acc_rz[(m0)][1]   = MF(af0a, bf[1][0], acc_rz[(m0)][1]);                  \
    acc_rz[(m0)][1]   = MF(af0b, bf[1][1], acc_rz[(m0)][1]);                  \
    ACCN[(m0)]        = MF(af0a, bf[2][0], ACCN[(m0)]);                       \
    ACCN[(m0)]        = MF(af0b, bf[2][1], ACCN[(m0)]);                       \
    acc_rz[(m0)+1][0] = MF(af1a, bf[0][0], acc_rz[(m0)+1][0]);                \
    acc_rz[(m0)+1][0] = MF(af1b, bf[0][1], acc_rz[(m0)+1][0]);                \
    acc_rz[(m0)+1][1] = MF(af1a, bf[1][0], acc_rz[(m0)+1][1]);                \
    acc_rz[(m0)+1][1] = MF(af1b, bf[1][1], acc_rz[(m0)+1][1]);                \
    ACCN[(m0)+1]      = MF(af1a, bf[2][0], ACCN[(m0)+1]);                     \
    ACCN[(m0)+1]      = MF(af1b, bf[2][1], ACCN[(m0)+1]);                     \
    __builtin_amdgcn_s_setprio(0);                                            \
    TAIL;                                                                     \
    FENCE(); BAR();                                                           \
  }

#define COPY_TAIL                                                             \
  {                                                                           \
    VM(3);                                                                    \
    const int rr0 = 4 * t + ccp, rr1 = rr0 + 2;                               \
    const unsigned long long fwt = (t < 16) ? fw0 : fw1;                      \
    const bool nv0 = (fwt >> (rr0 & 63)) & 1ull;                              \
    const bool nv1 = (fwt >> (rr1 & 63)) & 1ull;                              \
    if ((t & 1) == 0) {                                                       \
      if (vY0) __builtin_nontemporal_store(cpY0, (f32x4*)&out[(size_t)sY0 * HDIM + ccol]); \
      if (vY1) __builtin_nontemporal_store(cpY1, (f32x4*)&out[(size_t)sY1 * HDIM + ccol]); \
      vX0 = nv0; vX1 = nv1; sX0 = cbase + rr0; sX1 = cbase + rr1;             \
      if (vX0) cpX0 = __builtin_nontemporal_load((const f32x4*)&mem[(size_t)sX0 * HDIM + ccol]); \
      if (vX1) cpX1 = __builtin_nontemporal_load((const f32x4*)&mem[(size_t)sX1 * HDIM + ccol]); \
    } else {                                                                  \
      if (vX0) __builtin_nontemporal_store(cpX0, (f32x4*)&out[(size_t)sX0 * HDIM + ccol]); \
      if (vX1) __builtin_nontemporal_store(cpX1, (f32x4*)&out[(size_t)sX1 * HDIM + ccol]); \
      vY0 = nv0; vY1 = nv1; sY0 = cbase + rr0; sY1 = cbase + rr1;             \
      if (vY0) cpY0 = __builtin_nontemporal_load((const f32x4*)&mem[(size_t)sY0 * HDIM + ccol]); \
      if (vY1) cpY1 = __builtin_nontemporal_load((const f32x4*)&mem[(size_t)sY1 * HDIM + ccol]); \
    }                                                                         \
  }

#define TILE_BODY(ACCN)                                                       \
  {                                                                           \
    const int cur = t & 1, nxt = cur ^ 1;                                     \
    const size_t buf = (size_t)cur * BUF, nbuf = (size_t)nxt * BUF;           \
    const size_t abase  = buf + (size_t)wm * 16384;                           \
    const size_t rzbase = buf + 32768 + (size_t)wn * 4096;                    \
    const size_t nbase  = buf + 49152 + (size_t)wn * 2048;                    \
    const int kt1 = (t + 1 < NT) ? t + 1 : NT - 1;                            \
    const int kt2 = (t + 2 < NT) ? t + 2 : NT - 1;                            \
    short8 bf[3][2];                                                          \
    bf[0][0] = LDF(rzbase, 0, foff0); bf[0][1] = LDF(rzbase, 0, foff1);       \
    bf[1][0] = LDF(rzbase, 1, foff0); bf[1][1] = LDF(rzbase, 1, foff1);       \
    bf[2][0] = LDF(nbase,  0, foff0); bf[2][1] = LDF(nbase,  0, foff1);       \
    PHASE(0, STAGE(pA0r0 + kt1 * 64, pA0r1 + kt1 * 64, nbuf), ;, ACCN)        \
    PHASE(2, STAGE(pA1r0 + kt1 * 64, pA1r1 + kt1 * 64, nbuf + 16384), ;, ACCN)\
    PHASE(4, STAGE(pRZ0 + kt2 * 64, pRZ1 + kt2 * 64, buf + 32768), ;, ACCN)   \
    PHASE(6, STAGE1(pN + kt2 * 64, buf + 49152), COPY_TAIL, ACCN)             \
  }

__global__ __launch_bounds__(512, 2)
void k_gru8(const unsigned short* __restrict__ Ac,
            const unsigned short* __restrict__ Brz,
            const unsigned short* __restrict__ Bn,
            const float* __restrict__ mem,
            const int* __restrict__ sid,
            const int* __restrict__ lp,
            const unsigned long long* __restrict__ flagb,
            const float* __restrict__ btab,
            float* __restrict__ out) {
  extern __shared__ char smem[];

  const int tid  = threadIdx.x;
  const int lane = tid & 63;
  const int w    = tid >> 6;
  const int wm   = w >> 2;        // M half (0..1)
  const int wn   = w & 3;         // N quarter (0..3): 16 j's
  const int l15  = lane & 15;
  const int l4   = lane >> 4;

  // XCD-aware swizzle (512 % 8 == 0 -> bijective)
  const int bid = blockIdx.x;
  const int swz = (bid & 7) * 64 + (bid >> 3);
  const int t0  = (swz >> 4) * 256;        // 32 M-blocks
  const int j0  = (swz & 15) * 64;         // 16 J-blocks
  const int rz0 = j0 * 2;

  // ---- staging source mapping (inverse (row&7)<<4 swizzle folded in) ----
  const int srow0 = tid >> 3;              // 0..63
  const int srow1 = 64 + srow0;
  const int scol  = ((tid & 7) * 8) ^ (((tid >> 3) & 7) << 3);

  const unsigned short* pA0r0 = Ac + (size_t)(t0 +       srow0) * KDIM + scol;
  const unsigned short* pA0r1 = Ac + (size_t)(t0 +       srow1) * KDIM + scol;
  const unsigned short* pA1r0 = Ac + (size_t)(t0 + 128 + srow0) * KDIM + scol;
  const unsigned short* pA1r1 = Ac + (size_t)(t0 + 128 + srow1) * KDIM + scol;
  const unsigned short* pRZ0  = Brz + (size_t)(rz0 + srow0) * KDIM + scol;
  const unsigned short* pRZ1  = Brz + (size_t)(rz0 + srow1) * KDIM + scol;
  const unsigned short* pN    = Bn  + (size_t)(j0  + srow0) * KDIM + scol;

  // ---- fragment read offsets: col_byte ^= (row&7)<<4 ----
  const int rsw = (l15 & 7) << 4;
  const size_t foff0 = (size_t)l15 * 128 + ((l4 * 16)      ^ rsw);
  const size_t foff1 = (size_t)l15 * 128 + ((64 + l4 * 16) ^ rsw);

  f32x4 acc_rz[8][2], acc_nlo[8], acc_nhi[8];
#pragma unroll
  for (int i = 0; i < 8; i++) {
    acc_rz[i][0] = (f32x4){0.f,0.f,0.f,0.f};
    acc_rz[i][1] = (f32x4){0.f,0.f,0.f,0.f};
    acc_nlo[i]   = (f32x4){0.f,0.f,0.f,0.f};
    acc_nhi[i]   = (f32x4){0.f,0.f,0.f,0.f};
  }

  // ---- copy pipeline state (r10 scheme) ----
  const int cbase = bid << 7;
  const unsigned long long fw0 = flagb[bid * 2];
  const unsigned long long fw1 = flagb[bid * 2 + 1];
  const int ccp  = tid >> 8;
  const int ccol = (tid & 255) << 2;
  f32x4 cpX0, cpX1, cpY0, cpY1;
  bool  vX0 = false, vX1 = false, vY0 = false, vY1 = false;
  int   sX0 = 0, sX1 = 0, sY0 = 0, sY1 = 0;

  // ---- prologue: tile0 (A,Brz,Bn) + tile1 (Brz,Bn); VM(3) keeps B(1) in flight
  STAGE(pA0r0, pA0r1, 0);
  STAGE(pA1r0, pA1r1, 16384);
  STAGE(pRZ0, pRZ1, 32768);
  STAGE1(pN, 49152);
  STAGE(pRZ0 + 64, pRZ1 + 64, BUF + 32768);
  STAGE1(pN + 64, BUF + 49152);
  VM(3);
  FENCE(); BAR();

  for (int t = 0; t < 16; ++t) TILE_BODY(acc_nlo)     // k < 1024: i_n
  for (int t = 16; t < NT; ++t) TILE_BODY(acc_nhi)    // k >= 1024: h_n

  // ---- drain: final copy stores (t=31 odd -> set Y pending), then epilogue
  VM(0);
  if (vY0) __builtin_nontemporal_store(cpY0, (f32x4*)&out[(size_t)sY0 * HDIM + ccol]);
  if (vY1) __builtin_nontemporal_store(cpY1, (f32x4*)&out[(size_t)sY1 * HDIM + ccol]);
  __syncthreads();
  float* epi = (float*)smem;   // [8 waves][16 rows][68]: 16 j x {r,z,in,hn} + pad
  const int jfirst = j0 + wn * 16 + l4 * 4;

#pragma unroll
  for (int mf = 0; mf < 8; mf++) {
#pragma unroll
    for (int f = 0; f < 2; f++)
#pragma unroll
      for (int r = 0; r < 4; r++)
        epi[w * 1088 + (l4 * 4 + r) * 68 + (f * 8 + (l15 >> 1)) * 4 + (l15 & 1)] = acc_rz[mf][f][r];
#pragma unroll
    for (int r = 0; r < 4; r++) {
      epi[w * 1088 + (l4 * 4 + r) * 68 + l15 * 4 + 2] = acc_nlo[mf][r];
      epi[w * 1088 + (l4 * 4 + r) * 68 + l15 * 4 + 3] = acc_nhi[mf][r];
    }
    __syncthreads();

    const int trow = t0 + wm * 128 + mf * 16 + l15;
    const int s    = sid[trow];
    const bool wr  = (lp[s] == trow);

    f32x4 q[4];
#pragma unroll
    for (int jj = 0; jj < 4; jj++)
      q[jj] = *(const f32x4*)&epi[w * 1088 + l15 * 68 + l4 * 16 + jj * 4];

    f32x4 hv = *(const f32x4*)&mem[(size_t)s * HDIM + jfirst];
    f32x4 o;
#pragma unroll
    for (int jj = 0; jj < 4; jj++) {
      const int j = jfirst + jj;
      f32x4 bt = *(const f32x4*)&btab[4 * j];
      float rr = fast_sigmoid(q[jj][0] + bt[0]);
      float zz = fast_sigmoid(q[jj][1] + bt[1]);
      float nn = fast_tanh(q[jj][2] + bt[2] + rr * (q[jj][3] + bt[3]));
      o[jj] = (1.0f - zz) * nn + zz * hv[jj];
    }
    if (wr) __builtin_nontemporal_store(o, (f32x4*)&out[(size_t)s * HDIM + jfirst]);
    __syncthreads();
  }
}

// ---------------- launch ----------------

extern "C" void kernel_launch(void* const* d_in, const int* in_sizes, int n_in,
                              void* d_out, int out_size, void* d_ws, size_t ws_size,
                              hipStream_t stream) {
  const float* mem = (const float*)d_in[0];
  const int*   sid = (const int*)d_in[1];
  const float* edu = (const float*)d_in[2];
  const float* Wih = (const float*)d_in[3];
  const float* Whh = (const float*)d_in[4];
  const float* bih = (const float*)d_in[5];
  const float* bhh = (const float*)d_in[6];
  float* out = (float*)d_out;

  char* p = (char*)d_ws;
  unsigned short* Ac  = (unsigned short*)p; p += (size_t)TROWS * KDIM * 2;    // 32 MiB
  unsigned short* Brz = (unsigned short*)p; p += (size_t)2048 * KDIM * 2;     // 8 MiB
  unsigned short* Bn  = (unsigned short*)p; p += (size_t)1024 * KDIM * 2;     // 4 MiB
  int*   lp   = (int*)p;   p += (size_t)SROWS * 4;                            // 256 KiB
  float* btab = (float*)p; p += (size_t)HDIM * 4 * 4;                         // 16 KiB
  unsigned long long* flagb = (unsigned long long*)p; p += (size_t)(SROWS / 64) * 8; // 8 KiB

  hipFuncSetAttribute((const void*)k_gru8, hipFuncAttributeMaxDynamicSharedMemorySize, 2 * BUF);

  hipLaunchKernelGGL(k_initlp, dim3(SROWS / 256), dim3(256), 0, stream, lp);
  hipLaunchKernelGGL(k_lp, dim3(TROWS / 256), dim3(256), 0, stream, sid, lp);
  hipLaunchKernelGGL(k_flags, dim3(SROWS / 256), dim3(256), 0, stream, lp, flagb);
  hipLaunchKernelGGL(k_bias, dim3(4), dim3(256), 0, stream, bih, bhh, btab);
  hipLaunchKernelGGL(k_build_A, dim3((TROWS * KDIM / 8) / 256), dim3(256), 0, stream, edu, mem, sid, Ac);
  hipLaunchKernelGGL(k_build_B2, dim3(3072), dim3(256), 0, stream, Wih, Whh, Brz, Bn);
  hipLaunchKernelGGL(k_gru8, dim3(512), dim3(512), 2 * BUF, stream,
                     Ac, Brz, Bn, mem, sid, lp, flagb, btab, out);
}